// Round 1
// baseline (373.114 us; speedup 1.0000x reference)
//
#include <hip/hip_runtime.h>

#define BATCH 4096
#define FIELD 39
#define EMBED 16
#define NPAIRS (FIELD * (FIELD - 1))   // ordered pairs i != j: 1482
#define BLOCK 256
#define SLOTS (BLOCK / 4)              // 64 pair-slots per iteration
#define NITER ((NPAIRS + SLOTS - 1) / SLOTS)  // 24

__global__ __launch_bounds__(BLOCK) void ffm_kernel(
    const int*   __restrict__ idx,    // [B, F]
    const float* __restrict__ vals,   // [B, F]
    const float* __restrict__ emb,    // [100000, F, E]
    const float* __restrict__ w1,     // [100000, 1]
    const float* __restrict__ bias,   // [1]
    float*       __restrict__ out)    // [B, 1]
{
    const int b   = blockIdx.x;
    const int tid = threadIdx.x;

    __shared__ int   s_idx[FIELD];
    __shared__ float s_val[FIELD];
    __shared__ float s_red[4];

    if (tid < FIELD) {
        s_idx[tid] = idx[b * FIELD + tid];
        s_val[tid] = vals[b * FIELD + tid];
    }
    __syncthreads();

    float acc = 0.0f;

    // First-order term: threads 0..38 each add v_i * w1[idx_i]
    if (tid < FIELD) {
        acc += s_val[tid] * w1[s_idx[tid]];
    }

    // Second-order: ordered pairs (i,j), i != j; each contributes
    // 0.5 * v_i * v_j * dot(E[i][j], E[j][i]).  S is symmetric so the
    // ordered sum is exactly 2x the i<j sum.
    const float4* emb4 = (const float4*)emb;
    const int slot = tid >> 2;   // which pair this quarter handles
    const int e4   = tid & 3;    // which float4 of the 16-dim embedding

    #pragma unroll
    for (int it = 0; it < NITER; ++it) {
        int p = it * SLOTS + slot;
        if (p < NPAIRS) {
            int i = p / (FIELD - 1);
            int r = p - i * (FIELD - 1);
            int j = r + (r >= i ? 1 : 0);
            // E[i][j][:]  and  E[j][i][:], 16 floats each, float4 per lane
            float4 a = emb4[(s_idx[i] * FIELD + j) * (EMBED / 4) + e4];
            float4 c = emb4[(s_idx[j] * FIELD + i) * (EMBED / 4) + e4];
            float dot = a.x * c.x + a.y * c.y + a.z * c.z + a.w * c.w;
            acc += dot * (0.5f * s_val[i] * s_val[j]);
        }
    }

    // Wave (64-lane) shuffle reduction, then cross-wave via LDS
    #pragma unroll
    for (int off = 32; off > 0; off >>= 1)
        acc += __shfl_down(acc, off, 64);

    const int wave = tid >> 6;
    const int lane = tid & 63;
    if (lane == 0) s_red[wave] = acc;
    __syncthreads();

    if (tid == 0) {
        out[b] = s_red[0] + s_red[1] + s_red[2] + s_red[3] + bias[0];
    }
}

extern "C" void kernel_launch(void* const* d_in, const int* in_sizes, int n_in,
                              void* d_out, int out_size, void* d_ws, size_t ws_size,
                              hipStream_t stream) {
    const int*   idx  = (const int*)d_in[0];
    const float* vals = (const float*)d_in[1];
    const float* emb  = (const float*)d_in[2];
    const float* w1   = (const float*)d_in[3];
    const float* bias = (const float*)d_in[4];
    float* out = (float*)d_out;

    ffm_kernel<<<BATCH, BLOCK, 0, stream>>>(idx, vals, emb, w1, bias, out);
}

// Round 2
// 356.631 us; speedup vs baseline: 1.0462x; 1.0462x over previous
//
#include <hip/hip_runtime.h>
#include <hip/hip_fp16.h>

#define BATCH 4096
#define FIELD 39
#define EMBED 16
#define ROW_F4 (FIELD * EMBED / 4)        // 156 float4 per gathered embedding row (2496 B)
#define TOT_F4 (FIELD * ROW_F4)           // 6084 float4 staged per batch row
#define NPAIRS (FIELD * (FIELD - 1))      // 1482 ordered pairs (i != j)
#define NTASKS (NPAIRS * 4)               // 4 lanes per pair
#define BLOCK 512
#define NWAVES (BLOCK / 64)

__global__ __launch_bounds__(BLOCK) void ffm_kernel(
    const int*   __restrict__ idx,    // [B, F]
    const float* __restrict__ vals,   // [B, F]
    const float* __restrict__ emb,    // [100000, F, E]
    const float* __restrict__ w1,     // [100000, 1]
    const float* __restrict__ bias,   // [1]
    float*       __restrict__ out)    // [B, 1]
{
    const int b   = blockIdx.x;
    const int tid = threadIdx.x;

    // fp16 staging of the 39 gathered rows: 39*39*16 halves = 48672 B
    __shared__ __half s_emb[FIELD * FIELD * EMBED];
    __shared__ int    s_idx[FIELD];
    __shared__ float  s_val[FIELD];
    __shared__ float  s_red[NWAVES];

    if (tid < FIELD) {
        s_idx[tid] = idx[b * FIELD + tid];
        s_val[tid] = vals[b * FIELD + tid];
    }
    __syncthreads();

    // ---- Stage: 39 contiguous 2496 B blocks (coalesced), fp32 -> fp16 ----
    const float4* emb4 = (const float4*)emb;
    __half2* s2 = (__half2*)s_emb;
    for (int t = tid; t < TOT_F4; t += BLOCK) {
        int i   = t / ROW_F4;             // which field row (magic-mul)
        int off = t - i * ROW_F4;
        float4 g = emb4[s_idx[i] * ROW_F4 + off];
        s2[t * 2]     = __floats2half2_rn(g.x, g.y);
        s2[t * 2 + 1] = __floats2half2_rn(g.z, g.w);
    }

    float acc = 0.0f;
    // First-order term (uses only s_idx/s_val, synced above)
    if (tid < FIELD) {
        acc += s_val[tid] * w1[s_idx[tid]];
    }
    __syncthreads();  // s_emb ready

    // ---- Pairs from LDS: ordered (i,j), i!=j, 0.5x factor; 4 lanes/pair ----
    const int e = tid & 3;                // which 4-half chunk of the 16-dim embedding
    for (int t = tid; t < NTASKS; t += BLOCK) {
        int p = t >> 2;                   // pair index (t&3 == tid&3 since BLOCK%4==0)
        int i = p / (FIELD - 1);
        int r = p - i * (FIELD - 1);
        int j = r + (r >= i ? 1 : 0);
        const __half2* a2 = (const __half2*)&s_emb[(i * FIELD + j) * EMBED + e * 4];
        const __half2* c2 = (const __half2*)&s_emb[(j * FIELD + i) * EMBED + e * 4];
        float2 a0 = __half22float2(a2[0]);
        float2 a1 = __half22float2(a2[1]);
        float2 c0 = __half22float2(c2[0]);
        float2 c1 = __half22float2(c2[1]);
        float dot = a0.x * c0.x + a0.y * c0.y + a1.x * c1.x + a1.y * c1.y;
        acc += dot * (0.5f * s_val[i] * s_val[j]);
    }

    // ---- Reduce: 64-lane wave shuffle, then cross-wave via LDS ----
    #pragma unroll
    for (int off = 32; off > 0; off >>= 1)
        acc += __shfl_down(acc, off, 64);

    const int wave = tid >> 6;
    const int lane = tid & 63;
    if (lane == 0) s_red[wave] = acc;
    __syncthreads();

    if (tid == 0) {
        float s = 0.0f;
        #pragma unroll
        for (int w = 0; w < NWAVES; ++w) s += s_red[w];
        out[b] = s + bias[0];
    }
}

extern "C" void kernel_launch(void* const* d_in, const int* in_sizes, int n_in,
                              void* d_out, int out_size, void* d_ws, size_t ws_size,
                              hipStream_t stream) {
    const int*   idx  = (const int*)d_in[0];
    const float* vals = (const float*)d_in[1];
    const float* emb  = (const float*)d_in[2];
    const float* w1   = (const float*)d_in[3];
    const float* bias = (const float*)d_in[4];
    float* out = (float*)d_out;

    ffm_kernel<<<BATCH, BLOCK, 0, stream>>>(idx, vals, emb, w1, bias, out);
}

// Round 3
// 344.570 us; speedup vs baseline: 1.0828x; 1.0350x over previous
//
#include <hip/hip_runtime.h>
#include <hip/hip_fp16.h>

#define BATCH 4096
#define FIELD 39
#define EMBED 16
#define ROW_F4 (FIELD * EMBED / 4)        // 156 float4 per gathered row (2496 B)
#define TOT_F4 (FIELD * ROW_F4)           // 6084 float4 staged per batch row
#define NPAIRS (FIELD * (FIELD - 1))      // 1482 ordered pairs (i != j)
#define NTASK2 (NPAIRS * 2)               // 2964: 2 lanes per pair
#define BLOCK 1024
#define NWAVES (BLOCK / 64)               // 16
#define SITER ((TOT_F4 + BLOCK - 1) / BLOCK)  // 6
#define CITER ((NTASK2 + BLOCK - 1) / BLOCK)  // 3

// __launch_bounds__(1024, 8): 8 waves/EU -> 32 waves/CU -> 2 blocks/CU
// (LDS 48.7 KB x2 = 97.4 KB < 160 KB). Forces VGPR <= 64.
__global__ __launch_bounds__(BLOCK, 8) void ffm_kernel(
    const int*   __restrict__ idx,    // [B, F]
    const float* __restrict__ vals,   // [B, F]
    const float* __restrict__ emb,    // [100000, F, E]
    const float* __restrict__ w1,     // [100000, 1]
    const float* __restrict__ bias,   // [1]
    float*       __restrict__ out)    // [B, 1]
{
    const int b   = blockIdx.x;
    const int tid = threadIdx.x;

    __shared__ __align__(16) __half s_emb[FIELD * FIELD * EMBED];  // 48672 B
    __shared__ int    s_idx[FIELD];
    __shared__ float  s_val[FIELD];
    __shared__ float  s_red[NWAVES];

    if (tid < FIELD) {
        s_idx[tid] = idx[b * FIELD + tid];
        s_val[tid] = vals[b * FIELD + tid];
    }
    __syncthreads();

    // ---- Stage: issue all 6 gathers first (6-deep MLP/thread), then convert ----
    const float4* emb4 = (const float4*)emb;
    float4 g[SITER];
    #pragma unroll
    for (int it = 0; it < SITER; ++it) {
        int t  = tid + it * BLOCK;
        int tc = t < TOT_F4 ? t : TOT_F4 - 1;   // clamp: no divergence, dup load benign
        int i  = tc / ROW_F4;
        int off = tc - i * ROW_F4;
        g[it] = emb4[s_idx[i] * ROW_F4 + off];
    }

    // First-order term overlaps the gather latency
    float acc = 0.0f;
    if (tid < FIELD) {
        acc = s_val[tid] * w1[s_idx[tid]];
    }

    __half2* s2 = (__half2*)s_emb;
    #pragma unroll
    for (int it = 0; it < SITER; ++it) {
        int t = tid + it * BLOCK;
        if (t < TOT_F4) {
            s2[t * 2]     = __floats2half2_rn(g[it].x, g[it].y);
            s2[t * 2 + 1] = __floats2half2_rn(g[it].z, g[it].w);
        }
    }
    __syncthreads();

    // ---- Pairs from LDS: ordered (i,j), i!=j, 0.5x; 2 lanes/pair, b128 reads ----
    #pragma unroll
    for (int it = 0; it < CITER; ++it) {
        int t = tid + it * BLOCK;
        if (t < NTASK2) {
            int p = t >> 1;
            int h = t & 1;                    // which 8-half half of the embedding
            int i = p / (FIELD - 1);
            int r = p - i * (FIELD - 1);
            int j = r + (r >= i ? 1 : 0);
            float4 av = *(const float4*)&s_emb[(i * FIELD + j) * EMBED + h * 8];
            float4 cv = *(const float4*)&s_emb[(j * FIELD + i) * EMBED + h * 8];
            const __half2* ah = (const __half2*)&av;
            const __half2* ch = (const __half2*)&cv;
            float dot = 0.0f;
            #pragma unroll
            for (int k = 0; k < 4; ++k) {
                float2 a = __half22float2(ah[k]);
                float2 c = __half22float2(ch[k]);
                dot += a.x * c.x + a.y * c.y;
            }
            acc += dot * (0.5f * s_val[i] * s_val[j]);
        }
    }

    // ---- Reduce: 64-lane wave shuffle, then cross-wave via LDS ----
    #pragma unroll
    for (int off = 32; off > 0; off >>= 1)
        acc += __shfl_down(acc, off, 64);

    const int wave = tid >> 6;
    const int lane = tid & 63;
    if (lane == 0) s_red[wave] = acc;
    __syncthreads();

    if (tid == 0) {
        float s = 0.0f;
        #pragma unroll
        for (int w = 0; w < NWAVES; ++w) s += s_red[w];
        out[b] = s + bias[0];
    }
}

extern "C" void kernel_launch(void* const* d_in, const int* in_sizes, int n_in,
                              void* d_out, int out_size, void* d_ws, size_t ws_size,
                              hipStream_t stream) {
    const int*   idx  = (const int*)d_in[0];
    const float* vals = (const float*)d_in[1];
    const float* emb  = (const float*)d_in[2];
    const float* w1   = (const float*)d_in[3];
    const float* bias = (const float*)d_in[4];
    float* out = (float*)d_out;

    ffm_kernel<<<BATCH, BLOCK, 0, stream>>>(idx, vals, emb, w1, bias, out);
}